// Round 9
// baseline (366.882 us; speedup 1.0000x reference)
//
#include <hip/hip_runtime.h>

// PolyAttention on MI355X (gfx950).
// cvt f32->bf16 -> fused QKV GEMM (256x128, BK=32, triple-buffer LDS, counted
// vmcnt pipeline, rope fused in epilogue, V transposed) -> causal poly(^4)
// attention (V-in-registers, K double-buffered, counted-vmcnt pipeline)
// -> output GEMM.  b=2, n=2048, d=2048, h=16, hd=128.

typedef __bf16 bf16;
typedef __bf16 bf16x8 __attribute__((ext_vector_type(8)));
typedef __bf16 bf16x4 __attribute__((ext_vector_type(4)));
typedef float f32x4 __attribute__((ext_vector_type(4)));

#define GLD(g, l)                                                   \
  __builtin_amdgcn_global_load_lds(                                 \
      (const __attribute__((address_space(1))) void*)(g),           \
      (__attribute__((address_space(3))) void*)(l), 16, 0, 0)

#define MFMA(a, b, c) __builtin_amdgcn_mfma_f32_16x16x32_bf16(a, b, c, 0, 0, 0)

// ---------- f32 -> bf16 conversion, 4 elems/thread ----------
__global__ __launch_bounds__(256) void k_cvt(const float* __restrict__ in,
                                             bf16* __restrict__ out, int n4) {
  int i = blockIdx.x * 256 + threadIdx.x;
  if (i >= n4) return;
  float4 v = reinterpret_cast<const float4*>(in)[i];
  bf16x4 o = {(bf16)v.x, (bf16)v.y, (bf16)v.z, (bf16)v.w};
  reinterpret_cast<bf16x4*>(out)[i] = o;
}

// ---------- 3x weight cvt into concatenated wqkv (6144 x 2048) ----------
__global__ __launch_bounds__(256) void k_cvt3(const float* __restrict__ a,
                                              const float* __restrict__ b,
                                              const float* __restrict__ c,
                                              bf16* __restrict__ out) {
  int i = blockIdx.x * 256 + threadIdx.x;
  const float* src = (i < 1048576) ? a : ((i < 2097152) ? b : c);
  int off = i & 1048575;
  float4 v = reinterpret_cast<const float4*>(src)[off];
  bf16x4 o = {(bf16)v.x, (bf16)v.y, (bf16)v.z, (bf16)v.w};
  reinterpret_cast<bf16x4*>(out)[i] = o;
}

// ---------- RoPE cos/sin table: (n=2048, half=64) ----------
__global__ __launch_bounds__(256) void k_rope_tab(float* __restrict__ ct,
                                                  float* __restrict__ st) {
  int i = blockIdx.x * 256 + threadIdx.x;
  if (i >= 2048 * 64) return;
  int pos = i >> 6, f = i & 63;
  float theta = exp2f(-(float)f * 0.20762050593046014f);  // 10000^(-f/64)
  float ang = (float)pos * theta;
  ct[i] = cosf(ang);
  st[i] = sinf(ang);
}

// ---------- fused QKV GEMM + rope epilogue (round-4 version, kept) ----------
__global__ __launch_bounds__(256, 2) void k_gemm_qkv(
    const bf16* __restrict__ Am, const bf16* __restrict__ Bm,
    bf16* __restrict__ Qp, bf16* __restrict__ Kp, bf16* __restrict__ Vt,
    const float* __restrict__ ct, const float* __restrict__ st) {
  __shared__ __align__(16) char LDS[73728];  // 3 x (16KB A + 8KB B)
  const int tid = threadIdx.x, w = tid >> 6, l = tid & 63;
  const int lr = l & 15, g = l >> 4;
  const int wr = w >> 1, wc = w & 1;
  const int tm = blockIdx.y * 256, tn = blockIdx.x * 128;

  const int rl = tid >> 2;
  const int scol = (((tid & 3) ^ (rl & 3) ^ ((rl >> 2) & 3)) << 3);
  const int xo = ((g ^ (lr & 3) ^ ((lr >> 2) & 3)) << 4);

#define STAGEQ(buf, kt)                                                      \
  {                                                                          \
    _Pragma("unroll") for (int i = 0; i < 4; ++i)                            \
        GLD(Am + (size_t)(tm + i * 64 + rl) * 2048 + (kt) + scol,            \
            LDS + (buf) * 24576 + i * 4096 + tid * 16);                      \
    _Pragma("unroll") for (int i = 0; i < 2; ++i)                            \
        GLD(Bm + (size_t)(tn + i * 64 + rl) * 2048 + (kt) + scol,            \
            LDS + (buf) * 24576 + 16384 + i * 4096 + tid * 16);              \
  }

  f32x4 acc[8][4] = {};

  STAGEQ(0, 0);
  STAGEQ(1, 32);
  int cur = 0, st3 = 2;
  for (int t = 0; t < 63; ++t) {
    asm volatile("s_waitcnt vmcnt(6)" ::: "memory");
    __builtin_amdgcn_s_barrier();
    asm volatile("" ::: "memory");
    if (t < 62) STAGEQ(st3, (t + 2) * 32);
    const char* pa = LDS + cur * 24576;
    const char* pb = pa + 16384;
    bf16x8 a[8], b[4];
#pragma unroll
    for (int fm = 0; fm < 8; ++fm)
      a[fm] = *reinterpret_cast<const bf16x8*>(pa + (wr * 128 + fm * 16 + lr) * 64 + xo);
#pragma unroll
    for (int nf = 0; nf < 4; ++nf)
      b[nf] = *reinterpret_cast<const bf16x8*>(pb + (wc * 64 + nf * 16 + lr) * 64 + xo);
    __builtin_amdgcn_s_setprio(1);
#pragma unroll
    for (int fm = 0; fm < 8; ++fm)
#pragma unroll
      for (int nf = 0; nf < 4; ++nf)
        acc[fm][nf] = MFMA(a[fm], b[nf], acc[fm][nf]);
    __builtin_amdgcn_s_setprio(0);
    cur = (cur == 2) ? 0 : cur + 1;
    st3 = (st3 == 2) ? 0 : st3 + 1;
  }
  {  // peeled last tile
    asm volatile("s_waitcnt vmcnt(0)" ::: "memory");
    __builtin_amdgcn_s_barrier();
    asm volatile("" ::: "memory");
    const char* pa = LDS + cur * 24576;
    const char* pb = pa + 16384;
    bf16x8 a[8], b[4];
#pragma unroll
    for (int fm = 0; fm < 8; ++fm)
      a[fm] = *reinterpret_cast<const bf16x8*>(pa + (wr * 128 + fm * 16 + lr) * 64 + xo);
#pragma unroll
    for (int nf = 0; nf < 4; ++nf)
      b[nf] = *reinterpret_cast<const bf16x8*>(pb + (wc * 64 + nf * 16 + lr) * 64 + xo);
#pragma unroll
    for (int fm = 0; fm < 8; ++fm)
#pragma unroll
      for (int nf = 0; nf < 4; ++nf)
        acc[fm][nf] = MFMA(a[fm], b[nf], acc[fm][nf]);
  }

  if (tn < 4096) {
    __syncthreads();
    bf16* E = (bf16*)LDS;  // [256][136]
#pragma unroll
    for (int fm = 0; fm < 8; ++fm)
#pragma unroll
      for (int nf = 0; nf < 4; ++nf)
#pragma unroll
        for (int rr = 0; rr < 4; ++rr)
          E[(wr * 128 + fm * 16 + g * 4 + rr) * 136 + wc * 64 + nf * 16 + lr] =
              (bf16)acc[fm][nf][rr];
    __syncthreads();
    const int hh = (tn & 2047) >> 7;
    bf16* dst = (tn < 2048) ? Qp : Kp;
#pragma unroll
    for (int i = 0; i < 16; ++i) {
      int task = i * 256 + tid;
      int row = task >> 4, dg = (task & 15) << 2;
      int token = tm + row, nn = token & 2047, bb = token >> 11;
      f32x4 c4 = *reinterpret_cast<const f32x4*>(ct + nn * 64 + dg);
      f32x4 s4 = *reinterpret_cast<const f32x4*>(st + nn * 64 + dg);
      bf16x4 x1 = *reinterpret_cast<const bf16x4*>(E + row * 136 + dg);
      bf16x4 x2 = *reinterpret_cast<const bf16x4*>(E + row * 136 + 64 + dg);
      bf16x4 o1, o2;
#pragma unroll
      for (int j = 0; j < 4; ++j) {
        float a1 = (float)x1[j], a2 = (float)x2[j];
        o1[j] = (bf16)(a1 * c4[j] - a2 * s4[j]);
        o2[j] = (bf16)(a1 * s4[j] + a2 * c4[j]);
      }
      size_t rb = (((size_t)bb * 16 + hh) * 2048 + nn) * 128;
      *reinterpret_cast<bf16x4*>(dst + rb + dg) = o1;
      *reinterpret_cast<bf16x4*>(dst + rb + 64 + dg) = o2;
    }
  } else {
#pragma unroll
    for (int fm = 0; fm < 8; ++fm)
#pragma unroll
      for (int nf = 0; nf < 4; ++nf) {
        int row0 = tm + wr * 128 + fm * 16 + g * 4;
        int col = (tn - 4096) + wc * 64 + nf * 16 + lr;
        int bb = row0 >> 11, nn = row0 & 2047;
        int hh = col >> 7, dd = col & 127;
        bf16x4 o = {(bf16)acc[fm][nf][0], (bf16)acc[fm][nf][1],
                    (bf16)acc[fm][nf][2], (bf16)acc[fm][nf][3]};
        *reinterpret_cast<bf16x4*>(
            Vt + (((size_t)bb * 16 + hh) * 128 + dd) * 2048 + nn) = o;
      }
  }
}

// ---------- output GEMM: C(f32) = A * B^T, 4096x2048x2048 (round-4, kept) ----------
__global__ __launch_bounds__(256, 3) void k_gemm_out(const bf16* __restrict__ Am,
                                                     const bf16* __restrict__ Bm,
                                                     float* __restrict__ C) {
  __shared__ __align__(16) char LDS[49152];
  const int tid = threadIdx.x, w = tid >> 6, l = tid & 63;
  const int lr = l & 15, g = l >> 4;
  const int wr = w >> 1, wc = w & 1;
  const int tm = blockIdx.y * 128, tn = blockIdx.x * 128;

  const int rl = tid >> 2;
  const int scol = (((tid & 3) ^ (rl & 3) ^ ((rl >> 2) & 3)) << 3);
  const int xo = ((g ^ (lr & 3) ^ ((lr >> 2) & 3)) << 4);

#define STAGEO(buf, kt)                                                      \
  {                                                                          \
    _Pragma("unroll") for (int i = 0; i < 2; ++i)                            \
        GLD(Am + (size_t)(tm + i * 64 + rl) * 2048 + (kt) + scol,            \
            LDS + (buf) * 16384 + i * 4096 + tid * 16);                      \
    _Pragma("unroll") for (int i = 0; i < 2; ++i)                            \
        GLD(Bm + (size_t)(tn + i * 64 + rl) * 2048 + (kt) + scol,            \
            LDS + (buf) * 16384 + 8192 + i * 4096 + tid * 16);               \
  }

  f32x4 acc[4][4] = {};

  STAGEO(0, 0);
  STAGEO(1, 32);
  int cur = 0, st3 = 2;
  for (int t = 0; t < 63; ++t) {
    asm volatile("s_waitcnt vmcnt(4)" ::: "memory");
    __builtin_amdgcn_s_barrier();
    asm volatile("" ::: "memory");
    if (t < 62) STAGEO(st3, (t + 2) * 32);
    const char* pa = LDS + cur * 16384;
    const char* pb = pa + 8192;
    bf16x8 a[4], b[4];
#pragma unroll
    for (int fm = 0; fm < 4; ++fm)
      a[fm] = *reinterpret_cast<const bf16x8*>(pa + (wr * 64 + fm * 16 + lr) * 64 + xo);
#pragma unroll
    for (int nf = 0; nf < 4; ++nf)
      b[nf] = *reinterpret_cast<const bf16x8*>(pb + (wc * 64 + nf * 16 + lr) * 64 + xo);
    __builtin_amdgcn_s_setprio(1);
#pragma unroll
    for (int fm = 0; fm < 4; ++fm)
#pragma unroll
      for (int nf = 0; nf < 4; ++nf)
        acc[fm][nf] = MFMA(a[fm], b[nf], acc[fm][nf]);
    __builtin_amdgcn_s_setprio(0);
    cur = (cur == 2) ? 0 : cur + 1;
    st3 = (st3 == 2) ? 0 : st3 + 1;
  }
  {
    asm volatile("s_waitcnt vmcnt(0)" ::: "memory");
    __builtin_amdgcn_s_barrier();
    asm volatile("" ::: "memory");
    const char* pa = LDS + cur * 16384;
    const char* pb = pa + 8192;
    bf16x8 a[4], b[4];
#pragma unroll
    for (int fm = 0; fm < 4; ++fm)
      a[fm] = *reinterpret_cast<const bf16x8*>(pa + (wr * 64 + fm * 16 + lr) * 64 + xo);
#pragma unroll
    for (int nf = 0; nf < 4; ++nf)
      b[nf] = *reinterpret_cast<const bf16x8*>(pb + (wc * 64 + nf * 16 + lr) * 64 + xo);
#pragma unroll
    for (int fm = 0; fm < 4; ++fm)
#pragma unroll
      for (int nf = 0; nf < 4; ++nf)
        acc[fm][nf] = MFMA(a[fm], b[nf], acc[fm][nf]);
  }

#pragma unroll
  for (int fm = 0; fm < 4; ++fm)
#pragma unroll
    for (int nf = 0; nf < 4; ++nf)
#pragma unroll
      for (int rr = 0; rr < 4; ++rr) {
        int row = tm + wr * 64 + fm * 16 + g * 4 + rr;
        int col = tn + wc * 64 + nf * 16 + lr;
        C[(size_t)row * 2048 + col] = acc[fm][nf][rr];
      }
}

// ---------- causal poly^4 attention ----------
// V in registers (global->reg, issued early; QK hides latency). K double-
// buffered in LDS, staged 1 tile ahead; counted gates vmcnt(40)/vmcnt(8)
// keep the vmem queue non-empty. Ps own-wave-rows only (no Ps barrier).
// LDS 80KB -> 2 blocks/CU. Denominator via MFMA ones-column.
__global__ __launch_bounds__(256) void k_attn(const bf16* __restrict__ Q,
                                              const bf16* __restrict__ K,
                                              const bf16* __restrict__ Vt,
                                              bf16* __restrict__ O) {
  __shared__ __align__(16) bf16 Ks[2][128 * 128];  // 64KB
  __shared__ __align__(16) bf16 Ps[64 * 128];      // 16KB
  const int tid = threadIdx.x, w = tid >> 6, l = tid & 63;
  const int lr = l & 15, g = l >> 4;
  const int flat = blockIdx.x;
  const int pair = flat >> 5, bh = flat & 31;
  const size_t base = (size_t)bh * 2048 * 128;
  const int b_ = bh >> 4, h_ = bh & 15;

  // ones B-fragment: output col 0 = row-sum of A (denominator)
  bf16x8 vones = {};
  if (lr == 0) {
#pragma unroll
    for (int j = 0; j < 8; ++j) vones[j] = (bf16)1.0f;
  }

#define STAGEK(tt, buf)                                              \
  {                                                                  \
    const bf16* kg = K + base + (size_t)(tt) * 128 * 128;            \
    _Pragma("unroll") for (int r = 0; r < 8; ++r) {                  \
      int e = r * 2048 + w * 512 + l * 8;                            \
      int row = e >> 7, cc = (e >> 3) & 15;                          \
      GLD(kg + (row << 7) + (((cc ^ (row & 7))) << 3),               \
          Ks[buf] + r * 2048 + w * 512);                             \
    }                                                                \
  }

  for (int seg = 0; seg < 2; ++seg) {
    const int qt = seg ? (31 - pair) : pair;
    const int qbase = qt * 64;
    bf16x8 qf[4];
#pragma unroll
    for (int kc = 0; kc < 4; ++kc)
      qf[kc] = *reinterpret_cast<const bf16x8*>(
          Q + base + (size_t)(qbase + w * 16 + lr) * 128 + kc * 32 + g * 8);

    f32x4 on[8] = {};
    f32x4 dn4 = {0.f, 0.f, 0.f, 0.f};
    const int nt = (qbase >> 7) + 1;

    // prologue: everyone done with previous seg's Ks, then stage K(0)
    __builtin_amdgcn_s_barrier();
    STAGEK(0, 0);

    for (int t = 0; t < nt; ++t) {
      // issue V(t) fragment loads -> registers (32 x 16B per lane)
      bf16x8 vb[4][8];
#pragma unroll
      for (int kc = 0; kc < 4; ++kc)
#pragma unroll
        for (int ni = 0; ni < 8; ++ni)
          vb[kc][ni] = *reinterpret_cast<const bf16x8*>(
              Vt + base + (size_t)(ni * 16 + lr) * 2048 + t * 128 + kc * 32 + g * 8);

      // barrier A: everyone finished reading Ks[(t+1)&1] (tile t-1's QK)
      __builtin_amdgcn_s_barrier();
      int tn1 = (t + 1 < nt) ? t + 1 : nt - 1;  // clamped dummy keeps counts uniform
      STAGEK(tn1, (t + 1) & 1);
      asm volatile("s_waitcnt vmcnt(40)" ::: "memory");  // own K(t) landed
      __builtin_amdgcn_s_barrier();                      // everyone's K(t) landed

      // S = Q K^T from Ks[t&1]
      const bf16* kcur = Ks[t & 1];
      f32x4 s[8] = {};
      __builtin_amdgcn_s_setprio(1);
#pragma unroll
      for (int kc = 0; kc < 4; ++kc)
#pragma unroll
        for (int ni = 0; ni < 8; ++ni) {
          bf16x8 kb = *reinterpret_cast<const bf16x8*>(
              kcur + ((ni * 16 + lr) << 7) + (((kc * 4 + g) ^ (lr & 7)) << 3));
          s[ni] = MFMA(qf[kc], kb, s[ni]);
        }
      __builtin_amdgcn_s_setprio(0);

      // ^4 (+mask only on diagonal tile), swizzled Ps writes (own-wave rows)
      const bool diag = (t == nt - 1);
#pragma unroll
      for (int ni = 0; ni < 8; ++ni)
#pragma unroll
        for (int r = 0; r < 4; ++r) {
          int lrow = g * 4 + r;
          float v = s[ni][r];
          if (diag) {
            int qrow = qbase + w * 16 + lrow;
            int col = t * 128 + ni * 16 + lr;
            v = (col <= qrow) ? v : 0.f;
          }
          float v2 = v * v, v4 = v2 * v2;
          int chunk = ni * 2 + (lr >> 3);
          Ps[((w * 16 + lrow) << 7) + ((chunk ^ (lrow & 7)) << 3) + (lr & 7)] =
              (bf16)v4;
        }

      // V(t) landed (K(t+1) still in flight)
      asm volatile("s_waitcnt vmcnt(8)" ::: "memory");

      // O += P @ V ; dn4 += P @ ones  (A from own-wave Ps rows, B from regs)
      __builtin_amdgcn_s_setprio(1);
#pragma unroll
      for (int kc = 0; kc < 4; ++kc) {
        bf16x8 pa = *reinterpret_cast<const bf16x8*>(
            Ps + ((w * 16 + lr) << 7) + (((kc * 4 + g) ^ (lr & 7)) << 3));
        dn4 = MFMA(pa, vones, dn4);
#pragma unroll
        for (int ni = 0; ni < 8; ++ni)
          on[ni] = MFMA(pa, vb[kc][ni], on[ni]);
      }
      __builtin_amdgcn_s_setprio(0);
    }

    // epilogue: broadcast denom from the lr==0 lane of this g-group
#pragma unroll
    for (int r = 0; r < 4; ++r) {
      float d = __shfl(dn4[r], l & 48);
      float inv = 1.0f / fmaxf(d, 1e-6f);
      int row = qbase + w * 16 + g * 4 + r;
#pragma unroll
      for (int ni = 0; ni < 8; ++ni)
        O[((size_t)b_ * 2048 + row) * 2048 + h_ * 128 + ni * 16 + lr] =
            (bf16)(on[ni][r] * inv);
    }
  }
#undef STAGEK
}

extern "C" void kernel_launch(void* const* d_in, const int* in_sizes, int n_in,
                              void* d_out, int out_size, void* d_ws, size_t ws_size,
                              hipStream_t stream) {
  const float* x  = (const float*)d_in[0];
  const float* Wq = (const float*)d_in[1];
  const float* Wk = (const float*)d_in[2];
  const float* Wv = (const float*)d_in[3];
  const float* Wo = (const float*)d_in[4];
  float* out = (float*)d_out;

  char* p = (char*)d_ws;
  bf16* xb   = (bf16*)p; p += (size_t)8388608 * 2;    // x bf16 (4096x2048)
  bf16* wqkv = (bf16*)p; p += (size_t)12582912 * 2;   // [Wq;Wk;Wv] (6144x2048)
  bf16* wob  = (bf16*)p; p += (size_t)4194304 * 2;    // Wo bf16
  bf16* Qp   = (bf16*)p; p += (size_t)8388608 * 2;    // roped (b,h,n,128)
  bf16* Kp   = (bf16*)p; p += (size_t)8388608 * 2;    // roped (b,h,n,128)
  bf16* Vt   = (bf16*)p; p += (size_t)8388608 * 2;    // (b,h,128,n)
  bf16* Ob   = (bf16*)p; p += (size_t)8388608 * 2;    // attn out (b,n,h*128)
  float* ct  = (float*)p; p += (size_t)131072 * 4;
  float* st  = (float*)p; p += (size_t)131072 * 4;

  k_cvt<<<8192, 256, 0, stream>>>(x, xb, 2097152);
  k_cvt3<<<12288, 256, 0, stream>>>(Wq, Wk, Wv, wqkv);
  k_cvt<<<4096, 256, 0, stream>>>(Wo, wob, 1048576);
  k_rope_tab<<<512, 256, 0, stream>>>(ct, st);

  k_gemm_qkv<<<dim3(48, 16), 256, 0, stream>>>(xb, wqkv, Qp, Kp, Vt, ct, st);

  k_attn<<<512, 256, 0, stream>>>(Qp, Kp, Vt, Ob);

  k_gemm_out<<<dim3(16, 32), 256, 0, stream>>>(Ob, wob, out);
}

// Round 10
// 254.311 us; speedup vs baseline: 1.4427x; 1.4427x over previous
//
#include <hip/hip_runtime.h>

// PolyAttention on MI355X (gfx950).
// cvt f32->bf16 -> fused QKV GEMM (256x128, BK=32, triple-buffer LDS, counted
// vmcnt pipeline, rope fused in epilogue, V transposed) -> causal poly(^4)
// attention (QBLK=128/mi=2, KVBLK=64, K+V double-buffered GLD pipeline)
// -> output GEMM.  b=2, n=2048, d=2048, h=16, hd=128.

typedef __bf16 bf16;
typedef __bf16 bf16x8 __attribute__((ext_vector_type(8)));
typedef __bf16 bf16x4 __attribute__((ext_vector_type(4)));
typedef float f32x4 __attribute__((ext_vector_type(4)));

#define GLD(g, l)                                                   \
  __builtin_amdgcn_global_load_lds(                                 \
      (const __attribute__((address_space(1))) void*)(g),           \
      (__attribute__((address_space(3))) void*)(l), 16, 0, 0)

#define MFMA(a, b, c) __builtin_amdgcn_mfma_f32_16x16x32_bf16(a, b, c, 0, 0, 0)

// ---------- f32 -> bf16 conversion, 4 elems/thread ----------
__global__ __launch_bounds__(256) void k_cvt(const float* __restrict__ in,
                                             bf16* __restrict__ out, int n4) {
  int i = blockIdx.x * 256 + threadIdx.x;
  if (i >= n4) return;
  float4 v = reinterpret_cast<const float4*>(in)[i];
  bf16x4 o = {(bf16)v.x, (bf16)v.y, (bf16)v.z, (bf16)v.w};
  reinterpret_cast<bf16x4*>(out)[i] = o;
}

// ---------- 3x weight cvt into concatenated wqkv (6144 x 2048) ----------
__global__ __launch_bounds__(256) void k_cvt3(const float* __restrict__ a,
                                              const float* __restrict__ b,
                                              const float* __restrict__ c,
                                              bf16* __restrict__ out) {
  int i = blockIdx.x * 256 + threadIdx.x;
  const float* src = (i < 1048576) ? a : ((i < 2097152) ? b : c);
  int off = i & 1048575;
  float4 v = reinterpret_cast<const float4*>(src)[off];
  bf16x4 o = {(bf16)v.x, (bf16)v.y, (bf16)v.z, (bf16)v.w};
  reinterpret_cast<bf16x4*>(out)[i] = o;
}

// ---------- RoPE cos/sin table: (n=2048, half=64) ----------
__global__ __launch_bounds__(256) void k_rope_tab(float* __restrict__ ct,
                                                  float* __restrict__ st) {
  int i = blockIdx.x * 256 + threadIdx.x;
  if (i >= 2048 * 64) return;
  int pos = i >> 6, f = i & 63;
  float theta = exp2f(-(float)f * 0.20762050593046014f);  // 10000^(-f/64)
  float ang = (float)pos * theta;
  ct[i] = cosf(ang);
  st[i] = sinf(ang);
}

// ---------- fused QKV GEMM + rope epilogue (round-4 version, kept) ----------
__global__ __launch_bounds__(256, 2) void k_gemm_qkv(
    const bf16* __restrict__ Am, const bf16* __restrict__ Bm,
    bf16* __restrict__ Qp, bf16* __restrict__ Kp, bf16* __restrict__ Vt,
    const float* __restrict__ ct, const float* __restrict__ st) {
  __shared__ __align__(16) char LDS[73728];  // 3 x (16KB A + 8KB B)
  const int tid = threadIdx.x, w = tid >> 6, l = tid & 63;
  const int lr = l & 15, g = l >> 4;
  const int wr = w >> 1, wc = w & 1;
  const int tm = blockIdx.y * 256, tn = blockIdx.x * 128;

  const int rl = tid >> 2;
  const int scol = (((tid & 3) ^ (rl & 3) ^ ((rl >> 2) & 3)) << 3);
  const int xo = ((g ^ (lr & 3) ^ ((lr >> 2) & 3)) << 4);

#define STAGEQ(buf, kt)                                                      \
  {                                                                          \
    _Pragma("unroll") for (int i = 0; i < 4; ++i)                            \
        GLD(Am + (size_t)(tm + i * 64 + rl) * 2048 + (kt) + scol,            \
            LDS + (buf) * 24576 + i * 4096 + tid * 16);                      \
    _Pragma("unroll") for (int i = 0; i < 2; ++i)                            \
        GLD(Bm + (size_t)(tn + i * 64 + rl) * 2048 + (kt) + scol,            \
            LDS + (buf) * 24576 + 16384 + i * 4096 + tid * 16);              \
  }

  f32x4 acc[8][4] = {};

  STAGEQ(0, 0);
  STAGEQ(1, 32);
  int cur = 0, st3 = 2;
  for (int t = 0; t < 63; ++t) {
    asm volatile("s_waitcnt vmcnt(6)" ::: "memory");
    __builtin_amdgcn_s_barrier();
    asm volatile("" ::: "memory");
    if (t < 62) STAGEQ(st3, (t + 2) * 32);
    const char* pa = LDS + cur * 24576;
    const char* pb = pa + 16384;
    bf16x8 a[8], b[4];
#pragma unroll
    for (int fm = 0; fm < 8; ++fm)
      a[fm] = *reinterpret_cast<const bf16x8*>(pa + (wr * 128 + fm * 16 + lr) * 64 + xo);
#pragma unroll
    for (int nf = 0; nf < 4; ++nf)
      b[nf] = *reinterpret_cast<const bf16x8*>(pb + (wc * 64 + nf * 16 + lr) * 64 + xo);
    __builtin_amdgcn_s_setprio(1);
#pragma unroll
    for (int fm = 0; fm < 8; ++fm)
#pragma unroll
      for (int nf = 0; nf < 4; ++nf)
        acc[fm][nf] = MFMA(a[fm], b[nf], acc[fm][nf]);
    __builtin_amdgcn_s_setprio(0);
    cur = (cur == 2) ? 0 : cur + 1;
    st3 = (st3 == 2) ? 0 : st3 + 1;
  }
  {  // peeled last tile
    asm volatile("s_waitcnt vmcnt(0)" ::: "memory");
    __builtin_amdgcn_s_barrier();
    asm volatile("" ::: "memory");
    const char* pa = LDS + cur * 24576;
    const char* pb = pa + 16384;
    bf16x8 a[8], b[4];
#pragma unroll
    for (int fm = 0; fm < 8; ++fm)
      a[fm] = *reinterpret_cast<const bf16x8*>(pa + (wr * 128 + fm * 16 + lr) * 64 + xo);
#pragma unroll
    for (int nf = 0; nf < 4; ++nf)
      b[nf] = *reinterpret_cast<const bf16x8*>(pb + (wc * 64 + nf * 16 + lr) * 64 + xo);
#pragma unroll
    for (int fm = 0; fm < 8; ++fm)
#pragma unroll
      for (int nf = 0; nf < 4; ++nf)
        acc[fm][nf] = MFMA(a[fm], b[nf], acc[fm][nf]);
  }

  if (tn < 4096) {
    __syncthreads();
    bf16* E = (bf16*)LDS;  // [256][136]
#pragma unroll
    for (int fm = 0; fm < 8; ++fm)
#pragma unroll
      for (int nf = 0; nf < 4; ++nf)
#pragma unroll
        for (int rr = 0; rr < 4; ++rr)
          E[(wr * 128 + fm * 16 + g * 4 + rr) * 136 + wc * 64 + nf * 16 + lr] =
              (bf16)acc[fm][nf][rr];
    __syncthreads();
    const int hh = (tn & 2047) >> 7;
    bf16* dst = (tn < 2048) ? Qp : Kp;
#pragma unroll
    for (int i = 0; i < 16; ++i) {
      int task = i * 256 + tid;
      int row = task >> 4, dg = (task & 15) << 2;
      int token = tm + row, nn = token & 2047, bb = token >> 11;
      f32x4 c4 = *reinterpret_cast<const f32x4*>(ct + nn * 64 + dg);
      f32x4 s4 = *reinterpret_cast<const f32x4*>(st + nn * 64 + dg);
      bf16x4 x1 = *reinterpret_cast<const bf16x4*>(E + row * 136 + dg);
      bf16x4 x2 = *reinterpret_cast<const bf16x4*>(E + row * 136 + 64 + dg);
      bf16x4 o1, o2;
#pragma unroll
      for (int j = 0; j < 4; ++j) {
        float a1 = (float)x1[j], a2 = (float)x2[j];
        o1[j] = (bf16)(a1 * c4[j] - a2 * s4[j]);
        o2[j] = (bf16)(a1 * s4[j] + a2 * c4[j]);
      }
      size_t rb = (((size_t)bb * 16 + hh) * 2048 + nn) * 128;
      *reinterpret_cast<bf16x4*>(dst + rb + dg) = o1;
      *reinterpret_cast<bf16x4*>(dst + rb + 64 + dg) = o2;
    }
  } else {
#pragma unroll
    for (int fm = 0; fm < 8; ++fm)
#pragma unroll
      for (int nf = 0; nf < 4; ++nf) {
        int row0 = tm + wr * 128 + fm * 16 + g * 4;
        int col = (tn - 4096) + wc * 64 + nf * 16 + lr;
        int bb = row0 >> 11, nn = row0 & 2047;
        int hh = col >> 7, dd = col & 127;
        bf16x4 o = {(bf16)acc[fm][nf][0], (bf16)acc[fm][nf][1],
                    (bf16)acc[fm][nf][2], (bf16)acc[fm][nf][3]};
        *reinterpret_cast<bf16x4*>(
            Vt + (((size_t)bb * 16 + hh) * 128 + dd) * 2048 + nn) = o;
      }
  }
}

// ---------- output GEMM: C(f32) = A * B^T, 4096x2048x2048 (round-4, kept) ----------
__global__ __launch_bounds__(256, 3) void k_gemm_out(const bf16* __restrict__ Am,
                                                     const bf16* __restrict__ Bm,
                                                     float* __restrict__ C) {
  __shared__ __align__(16) char LDS[49152];
  const int tid = threadIdx.x, w = tid >> 6, l = tid & 63;
  const int lr = l & 15, g = l >> 4;
  const int wr = w >> 1, wc = w & 1;
  const int tm = blockIdx.y * 128, tn = blockIdx.x * 128;

  const int rl = tid >> 2;
  const int scol = (((tid & 3) ^ (rl & 3) ^ ((rl >> 2) & 3)) << 3);
  const int xo = ((g ^ (lr & 3) ^ ((lr >> 2) & 3)) << 4);

#define STAGEO(buf, kt)                                                      \
  {                                                                          \
    _Pragma("unroll") for (int i = 0; i < 2; ++i)                            \
        GLD(Am + (size_t)(tm + i * 64 + rl) * 2048 + (kt) + scol,            \
            LDS + (buf) * 16384 + i * 4096 + tid * 16);                      \
    _Pragma("unroll") for (int i = 0; i < 2; ++i)                            \
        GLD(Bm + (size_t)(tn + i * 64 + rl) * 2048 + (kt) + scol,            \
            LDS + (buf) * 16384 + 8192 + i * 4096 + tid * 16);               \
  }

  f32x4 acc[4][4] = {};

  STAGEO(0, 0);
  STAGEO(1, 32);
  int cur = 0, st3 = 2;
  for (int t = 0; t < 63; ++t) {
    asm volatile("s_waitcnt vmcnt(4)" ::: "memory");
    __builtin_amdgcn_s_barrier();
    asm volatile("" ::: "memory");
    if (t < 62) STAGEO(st3, (t + 2) * 32);
    const char* pa = LDS + cur * 16384;
    const char* pb = pa + 8192;
    bf16x8 a[4], b[4];
#pragma unroll
    for (int fm = 0; fm < 4; ++fm)
      a[fm] = *reinterpret_cast<const bf16x8*>(pa + (wr * 64 + fm * 16 + lr) * 64 + xo);
#pragma unroll
    for (int nf = 0; nf < 4; ++nf)
      b[nf] = *reinterpret_cast<const bf16x8*>(pb + (wc * 64 + nf * 16 + lr) * 64 + xo);
    __builtin_amdgcn_s_setprio(1);
#pragma unroll
    for (int fm = 0; fm < 4; ++fm)
#pragma unroll
      for (int nf = 0; nf < 4; ++nf)
        acc[fm][nf] = MFMA(a[fm], b[nf], acc[fm][nf]);
    __builtin_amdgcn_s_setprio(0);
    cur = (cur == 2) ? 0 : cur + 1;
    st3 = (st3 == 2) ? 0 : st3 + 1;
  }
  {
    asm volatile("s_waitcnt vmcnt(0)" ::: "memory");
    __builtin_amdgcn_s_barrier();
    asm volatile("" ::: "memory");
    const char* pa = LDS + cur * 16384;
    const char* pb = pa + 8192;
    bf16x8 a[4], b[4];
#pragma unroll
    for (int fm = 0; fm < 4; ++fm)
      a[fm] = *reinterpret_cast<const bf16x8*>(pa + (wr * 64 + fm * 16 + lr) * 64 + xo);
#pragma unroll
    for (int nf = 0; nf < 4; ++nf)
      b[nf] = *reinterpret_cast<const bf16x8*>(pb + (wc * 64 + nf * 16 + lr) * 64 + xo);
#pragma unroll
    for (int fm = 0; fm < 4; ++fm)
#pragma unroll
      for (int nf = 0; nf < 4; ++nf)
        acc[fm][nf] = MFMA(a[fm], b[nf], acc[fm][nf]);
  }

#pragma unroll
  for (int fm = 0; fm < 4; ++fm)
#pragma unroll
    for (int nf = 0; nf < 4; ++nf)
#pragma unroll
      for (int rr = 0; rr < 4; ++rr) {
        int row = tm + wr * 64 + fm * 16 + g * 4 + rr;
        int col = tn + wc * 64 + nf * 16 + lr;
        C[(size_t)row * 2048 + col] = acc[fm][nf][rr];
      }
}

// ---------- causal poly^4 attention ----------
// QBLK=128 (4 waves x 32 rows, mi=2) raises MFMA:ds_read to ~2:1 (B-frags
// amortized over mi). KVBLK=64, K+V double-buffered (80KB, 2 blocks/CU),
// coalesced GLD staging 1 tile ahead, single vmcnt(8) gate per tile (queue
// never drains mid-loop). Ps own-wave rows only. MFMA ones-column denominator.
// Grid 512 unpaired, longest q-block first (all blocks co-resident).
__global__ __launch_bounds__(256) void k_attn(const bf16* __restrict__ Q,
                                              const bf16* __restrict__ K,
                                              const bf16* __restrict__ Vt,
                                              bf16* __restrict__ O) {
  __shared__ __align__(16) bf16 Ks[2][64 * 128];  // 32KB
  __shared__ __align__(16) bf16 Vs[2][128 * 64];  // 32KB  [hd][kv]
  __shared__ __align__(16) bf16 Ps[128 * 64];     // 16KB
  const int tid = threadIdx.x, w = tid >> 6, l = tid & 63;
  const int lr = l & 15, g = l >> 4;
  const int qb = 15 - (blockIdx.x >> 5);  // longest first
  const int bh = blockIdx.x & 31;
  const size_t base = (size_t)bh * 2048 * 128;
  const int b_ = bh >> 4, h_ = bh & 15;
  const int qbase = qb * 128;
  const int nt = 2 * qb + 2;

  bf16x8 vones = {};
  if (lr == 0) {
#pragma unroll
    for (int j = 0; j < 8; ++j) vones[j] = (bf16)1.0f;
  }

  // Q fragments: wave w rows qbase + w*32 + mi*16 + lr
  bf16x8 qf[2][4];
#pragma unroll
  for (int mi = 0; mi < 2; ++mi)
#pragma unroll
    for (int kc = 0; kc < 4; ++kc)
      qf[mi][kc] = *reinterpret_cast<const bf16x8*>(
          Q + base + (size_t)(qbase + w * 32 + mi * 16 + lr) * 128 + kc * 32 + g * 8);

  f32x4 on[2][8] = {};
  f32x4 dn4[2] = {};

  // stage K(64x128) + V(128x64) for kv-tile tt into buffer buf; 8 GLD units.
#define STAGEKV(tt, buf)                                                 \
  {                                                                      \
    const bf16* kg = K + base + (size_t)(tt) * 64 * 128;                 \
    _Pragma("unroll") for (int r = 0; r < 4; ++r) {                      \
      int row = r * 16 + w * 4 + (l >> 4);                               \
      int cc = l & 15;                                                   \
      GLD(kg + (row << 7) + ((cc ^ (row & 7)) << 3),                     \
          Ks[buf] + r * 2048 + w * 512);                                 \
    }                                                                    \
    const bf16* vg = Vt + base + (tt) * 64;                              \
    _Pragma("unroll") for (int r = 0; r < 4; ++r) {                      \
      int row = r * 32 + w * 8 + (l >> 3);                               \
      int cc = l & 7;                                                    \
      GLD(vg + (size_t)row * 2048 + ((cc ^ (row & 7)) << 3),             \
          Vs[buf] + r * 2048 + w * 512);                                 \
    }                                                                    \
  }

  STAGEKV(0, 0);

  for (int t = 0; t < nt; ++t) {
    int tn1 = (t + 1 < nt) ? t + 1 : nt - 1;  // clamped dummy keeps counts uniform
    STAGEKV(tn1, (t + 1) & 1);
    asm volatile("s_waitcnt vmcnt(8)" ::: "memory");  // tile t landed, t+1 flying
    __builtin_amdgcn_s_barrier();

    const bf16* kcur = Ks[t & 1];
    const bf16* vcur = Vs[t & 1];

    // S = Q K^T  (32 q-rows x 64 kv-cols per wave)
    f32x4 s[2][4] = {};
    __builtin_amdgcn_s_setprio(1);
#pragma unroll
    for (int kc = 0; kc < 4; ++kc) {
      bf16x8 kb[4];
#pragma unroll
      for (int ni = 0; ni < 4; ++ni)
        kb[ni] = *reinterpret_cast<const bf16x8*>(
            kcur + ((ni * 16 + lr) << 7) + (((kc * 4 + g) ^ (lr & 7)) << 3));
#pragma unroll
      for (int mi = 0; mi < 2; ++mi)
#pragma unroll
        for (int ni = 0; ni < 4; ++ni)
          s[mi][ni] = MFMA(qf[mi][kc], kb[ni], s[mi][ni]);
    }
    __builtin_amdgcn_s_setprio(0);

    // ^4 (+mask only where the tile crosses the diagonal), swizzled Ps writes
#pragma unroll
    for (int mi = 0; mi < 2; ++mi) {
      const bool msk = (t * 64 + 63 > qbase + w * 32 + mi * 16);
#pragma unroll
      for (int ni = 0; ni < 4; ++ni)
#pragma unroll
        for (int r = 0; r < 4; ++r) {
          int lrow = mi * 16 + g * 4 + r;
          float v = s[mi][ni][r];
          if (msk) {
            int qrow = qbase + w * 32 + lrow;
            int col = t * 64 + ni * 16 + lr;
            v = (col <= qrow) ? v : 0.f;
          }
          float v2 = v * v, v4 = v2 * v2;
          Ps[((w * 32 + lrow) << 6) +
             (((ni * 2 + (lr >> 3)) ^ (lrow & 7)) << 3) + (lr & 7)] = (bf16)v4;
        }
    }

    // O += P @ V ; dn += P @ ones  (own-wave Ps rows; Vs shared)
    __builtin_amdgcn_s_setprio(1);
#pragma unroll
    for (int k2 = 0; k2 < 2; ++k2) {
      bf16x8 pa[2];
#pragma unroll
      for (int mi = 0; mi < 2; ++mi)
        pa[mi] = *reinterpret_cast<const bf16x8*>(
            Ps + ((w * 32 + mi * 16 + lr) << 6) + (((k2 * 4 + g) ^ (lr & 7)) << 3));
      dn4[0] = MFMA(pa[0], vones, dn4[0]);
      dn4[1] = MFMA(pa[1], vones, dn4[1]);
#pragma unroll
      for (int ni = 0; ni < 8; ++ni) {
        bf16x8 vbf = *reinterpret_cast<const bf16x8*>(
            vcur + ((ni * 16 + lr) << 6) + (((k2 * 4 + g) ^ (lr & 7)) << 3));
        on[0][ni] = MFMA(pa[0], vbf, on[0][ni]);
        on[1][ni] = MFMA(pa[1], vbf, on[1][ni]);
      }
    }
    __builtin_amdgcn_s_setprio(0);
    __builtin_amdgcn_s_barrier();  // buf t free for overwrite next iter
  }

  asm volatile("s_waitcnt vmcnt(0)" ::: "memory");  // drain dummy stage (LDS reuse safety)

  // epilogue: broadcast denom from lr==0 lane of this g-group, divide, store
#pragma unroll
  for (int mi = 0; mi < 2; ++mi)
#pragma unroll
    for (int r = 0; r < 4; ++r) {
      float d = __shfl(dn4[mi][r], l & 48);
      float inv = 1.0f / fmaxf(d, 1e-6f);
      int row = qbase + w * 32 + mi * 16 + g * 4 + r;
#pragma unroll
      for (int ni = 0; ni < 8; ++ni)
        O[((size_t)b_ * 2048 + row) * 2048 + h_ * 128 + ni * 16 + lr] =
            (bf16)(on[mi][ni][r] * inv);
    }
#undef STAGEKV
}

extern "C" void kernel_launch(void* const* d_in, const int* in_sizes, int n_in,
                              void* d_out, int out_size, void* d_ws, size_t ws_size,
                              hipStream_t stream) {
  const float* x  = (const float*)d_in[0];
  const float* Wq = (const float*)d_in[1];
  const float* Wk = (const float*)d_in[2];
  const float* Wv = (const float*)d_in[3];
  const float* Wo = (const float*)d_in[4];
  float* out = (float*)d_out;

  char* p = (char*)d_ws;
  bf16* xb   = (bf16*)p; p += (size_t)8388608 * 2;    // x bf16 (4096x2048)
  bf16* wqkv = (bf16*)p; p += (size_t)12582912 * 2;   // [Wq;Wk;Wv] (6144x2048)
  bf16* wob  = (bf16*)p; p += (size_t)4194304 * 2;    // Wo bf16
  bf16* Qp   = (bf16*)p; p += (size_t)8388608 * 2;    // roped (b,h,n,128)
  bf16* Kp   = (bf16*)p; p += (size_t)8388608 * 2;    // roped (b,h,n,128)
  bf16* Vt   = (bf16*)p; p += (size_t)8388608 * 2;    // (b,h,128,n)
  bf16* Ob   = (bf16*)p; p += (size_t)8388608 * 2;    // attn out (b,n,h*128)
  float* ct  = (float*)p; p += (size_t)131072 * 4;
  float* st  = (float*)p; p += (size_t)131072 * 4;

  k_cvt<<<8192, 256, 0, stream>>>(x, xb, 2097152);
  k_cvt3<<<12288, 256, 0, stream>>>(Wq, Wk, Wv, wqkv);
  k_cvt<<<4096, 256, 0, stream>>>(Wo, wob, 1048576);
  k_rope_tab<<<512, 256, 0, stream>>>(ct, st);

  k_gemm_qkv<<<dim3(48, 16), 256, 0, stream>>>(xb, wqkv, Qp, Kp, Vt, ct, st);

  k_attn<<<512, 256, 0, stream>>>(Qp, Kp, Vt, Ob);

  k_gemm_out<<<dim3(16, 32), 256, 0, stream>>>(Ob, wob, out);
}

// Round 11
// 246.933 us; speedup vs baseline: 1.4858x; 1.0299x over previous
//
#include <hip/hip_runtime.h>

// PolyAttention on MI355X (gfx950).
// k_prep (fused cvt x/wqkv/wo + rope table) -> fused QKV GEMM (256x128, BK=32,
// triple-buffer, vmcnt(6) pipeline, rope fused, V transposed) -> causal poly^4
// attention (QBLK=128, KVBLK=64, K+V dbuf GLD pipeline) -> output GEMM
// (same 256x128 structure, f32 out).  b=2, n=2048, d=2048, h=16, hd=128.

typedef __bf16 bf16;
typedef __bf16 bf16x8 __attribute__((ext_vector_type(8)));
typedef __bf16 bf16x4 __attribute__((ext_vector_type(4)));
typedef float f32x4 __attribute__((ext_vector_type(4)));

#define GLD(g, l)                                                   \
  __builtin_amdgcn_global_load_lds(                                 \
      (const __attribute__((address_space(1))) void*)(g),           \
      (__attribute__((address_space(3))) void*)(l), 16, 0, 0)

#define MFMA(a, b, c) __builtin_amdgcn_mfma_f32_16x16x32_bf16(a, b, c, 0, 0, 0)

// ---------- fused prep: cvt x / wqkv / wo (f32->bf16) + rope cos/sin table ----
__global__ __launch_bounds__(256) void k_prep(
    const float* __restrict__ x, const float* __restrict__ Wq,
    const float* __restrict__ Wk, const float* __restrict__ Wv,
    const float* __restrict__ Wo, bf16* __restrict__ xb,
    bf16* __restrict__ wqkv, bf16* __restrict__ wob,
    float* __restrict__ ct, float* __restrict__ st) {
  const int b = blockIdx.x, tid = threadIdx.x;
  if (b < 8192) {  // x: 2097152 float4-groups
    int i = b * 256 + tid;
    float4 v = reinterpret_cast<const float4*>(x)[i];
    bf16x4 o = {(bf16)v.x, (bf16)v.y, (bf16)v.z, (bf16)v.w};
    reinterpret_cast<bf16x4*>(xb)[i] = o;
  } else if (b < 20480) {  // wqkv: 3145728 groups (Wq|Wk|Wv)
    int i = (b - 8192) * 256 + tid;
    const float* src = (i < 1048576) ? Wq : ((i < 2097152) ? Wk : Wv);
    float4 v = reinterpret_cast<const float4*>(src)[i & 1048575];
    bf16x4 o = {(bf16)v.x, (bf16)v.y, (bf16)v.z, (bf16)v.w};
    reinterpret_cast<bf16x4*>(wqkv)[i] = o;
  } else if (b < 24576) {  // wo: 1048576 groups
    int i = (b - 20480) * 256 + tid;
    float4 v = reinterpret_cast<const float4*>(Wo)[i];
    bf16x4 o = {(bf16)v.x, (bf16)v.y, (bf16)v.z, (bf16)v.w};
    reinterpret_cast<bf16x4*>(wob)[i] = o;
  } else {  // rope table: 131072 entries
    int i = (b - 24576) * 256 + tid;
    int pos = i >> 6, f = i & 63;
    float theta = exp2f(-(float)f * 0.20762050593046014f);  // 10000^(-f/64)
    float ang = (float)pos * theta;
    ct[i] = cosf(ang);
    st[i] = sinf(ang);
  }
}

// ---------- fused QKV GEMM + rope epilogue (round-4 structure, frozen) ----------
__global__ __launch_bounds__(256, 2) void k_gemm_qkv(
    const bf16* __restrict__ Am, const bf16* __restrict__ Bm,
    bf16* __restrict__ Qp, bf16* __restrict__ Kp, bf16* __restrict__ Vt,
    const float* __restrict__ ct, const float* __restrict__ st) {
  __shared__ __align__(16) char LDS[73728];  // 3 x (16KB A + 8KB B)
  const int tid = threadIdx.x, w = tid >> 6, l = tid & 63;
  const int lr = l & 15, g = l >> 4;
  const int wr = w >> 1, wc = w & 1;
  const int tm = blockIdx.y * 256, tn = blockIdx.x * 128;

  const int rl = tid >> 2;
  const int scol = (((tid & 3) ^ (rl & 3) ^ ((rl >> 2) & 3)) << 3);
  const int xo = ((g ^ (lr & 3) ^ ((lr >> 2) & 3)) << 4);

#define STAGEQ(buf, kt)                                                      \
  {                                                                          \
    _Pragma("unroll") for (int i = 0; i < 4; ++i)                            \
        GLD(Am + (size_t)(tm + i * 64 + rl) * 2048 + (kt) + scol,            \
            LDS + (buf) * 24576 + i * 4096 + tid * 16);                      \
    _Pragma("unroll") for (int i = 0; i < 2; ++i)                            \
        GLD(Bm + (size_t)(tn + i * 64 + rl) * 2048 + (kt) + scol,            \
            LDS + (buf) * 24576 + 16384 + i * 4096 + tid * 16);              \
  }

  f32x4 acc[8][4] = {};

  STAGEQ(0, 0);
  STAGEQ(1, 32);
  int cur = 0, st3 = 2;
  for (int t = 0; t < 63; ++t) {
    asm volatile("s_waitcnt vmcnt(6)" ::: "memory");
    __builtin_amdgcn_s_barrier();
    asm volatile("" ::: "memory");
    if (t < 62) STAGEQ(st3, (t + 2) * 32);
    const char* pa = LDS + cur * 24576;
    const char* pb = pa + 16384;
    bf16x8 a[8], b[4];
#pragma unroll
    for (int fm = 0; fm < 8; ++fm)
      a[fm] = *reinterpret_cast<const bf16x8*>(pa + (wr * 128 + fm * 16 + lr) * 64 + xo);
#pragma unroll
    for (int nf = 0; nf < 4; ++nf)
      b[nf] = *reinterpret_cast<const bf16x8*>(pb + (wc * 64 + nf * 16 + lr) * 64 + xo);
    __builtin_amdgcn_s_setprio(1);
#pragma unroll
    for (int fm = 0; fm < 8; ++fm)
#pragma unroll
      for (int nf = 0; nf < 4; ++nf)
        acc[fm][nf] = MFMA(a[fm], b[nf], acc[fm][nf]);
    __builtin_amdgcn_s_setprio(0);
    cur = (cur == 2) ? 0 : cur + 1;
    st3 = (st3 == 2) ? 0 : st3 + 1;
  }
  {  // peeled last tile
    asm volatile("s_waitcnt vmcnt(0)" ::: "memory");
    __builtin_amdgcn_s_barrier();
    asm volatile("" ::: "memory");
    const char* pa = LDS + cur * 24576;
    const char* pb = pa + 16384;
    bf16x8 a[8], b[4];
#pragma unroll
    for (int fm = 0; fm < 8; ++fm)
      a[fm] = *reinterpret_cast<const bf16x8*>(pa + (wr * 128 + fm * 16 + lr) * 64 + xo);
#pragma unroll
    for (int nf = 0; nf < 4; ++nf)
      b[nf] = *reinterpret_cast<const bf16x8*>(pb + (wc * 64 + nf * 16 + lr) * 64 + xo);
#pragma unroll
    for (int fm = 0; fm < 8; ++fm)
#pragma unroll
      for (int nf = 0; nf < 4; ++nf)
        acc[fm][nf] = MFMA(a[fm], b[nf], acc[fm][nf]);
  }

  if (tn < 4096) {
    __syncthreads();
    bf16* E = (bf16*)LDS;  // [256][136]
#pragma unroll
    for (int fm = 0; fm < 8; ++fm)
#pragma unroll
      for (int nf = 0; nf < 4; ++nf)
#pragma unroll
        for (int rr = 0; rr < 4; ++rr)
          E[(wr * 128 + fm * 16 + g * 4 + rr) * 136 + wc * 64 + nf * 16 + lr] =
              (bf16)acc[fm][nf][rr];
    __syncthreads();
    const int hh = (tn & 2047) >> 7;
    bf16* dst = (tn < 2048) ? Qp : Kp;
#pragma unroll
    for (int i = 0; i < 16; ++i) {
      int task = i * 256 + tid;
      int row = task >> 4, dg = (task & 15) << 2;
      int token = tm + row, nn = token & 2047, bb = token >> 11;
      f32x4 c4 = *reinterpret_cast<const f32x4*>(ct + nn * 64 + dg);
      f32x4 s4 = *reinterpret_cast<const f32x4*>(st + nn * 64 + dg);
      bf16x4 x1 = *reinterpret_cast<const bf16x4*>(E + row * 136 + dg);
      bf16x4 x2 = *reinterpret_cast<const bf16x4*>(E + row * 136 + 64 + dg);
      bf16x4 o1, o2;
#pragma unroll
      for (int j = 0; j < 4; ++j) {
        float a1 = (float)x1[j], a2 = (float)x2[j];
        o1[j] = (bf16)(a1 * c4[j] - a2 * s4[j]);
        o2[j] = (bf16)(a1 * s4[j] + a2 * c4[j]);
      }
      size_t rb = (((size_t)bb * 16 + hh) * 2048 + nn) * 128;
      *reinterpret_cast<bf16x4*>(dst + rb + dg) = o1;
      *reinterpret_cast<bf16x4*>(dst + rb + 64 + dg) = o2;
    }
  } else {
#pragma unroll
    for (int fm = 0; fm < 8; ++fm)
#pragma unroll
      for (int nf = 0; nf < 4; ++nf) {
        int row0 = tm + wr * 128 + fm * 16 + g * 4;
        int col = (tn - 4096) + wc * 64 + nf * 16 + lr;
        int bb = row0 >> 11, nn = row0 & 2047;
        int hh = col >> 7, dd = col & 127;
        bf16x4 o = {(bf16)acc[fm][nf][0], (bf16)acc[fm][nf][1],
                    (bf16)acc[fm][nf][2], (bf16)acc[fm][nf][3]};
        *reinterpret_cast<bf16x4*>(
            Vt + (((size_t)bb * 16 + hh) * 128 + dd) * 2048 + nn) = o;
      }
  }
}

// ---------- output GEMM: C(f32) = A*B^T, 4096x2048x2048 ----------
// Upgraded to the QKV 256x128 structure (per-wave 128x64: 25% fewer LDS
// bytes/FLOP than 64x64). Grid (16,16)=256 blocks, 1-2/CU.
__global__ __launch_bounds__(256, 2) void k_gemm_out(const bf16* __restrict__ Am,
                                                     const bf16* __restrict__ Bm,
                                                     float* __restrict__ C) {
  __shared__ __align__(16) char LDS[73728];  // 3 x (16KB A + 8KB B)
  const int tid = threadIdx.x, w = tid >> 6, l = tid & 63;
  const int lr = l & 15, g = l >> 4;
  const int wr = w >> 1, wc = w & 1;
  const int tm = blockIdx.y * 256, tn = blockIdx.x * 128;

  const int rl = tid >> 2;
  const int scol = (((tid & 3) ^ (rl & 3) ^ ((rl >> 2) & 3)) << 3);
  const int xo = ((g ^ (lr & 3) ^ ((lr >> 2) & 3)) << 4);

#define STAGEU(buf, kt)                                                      \
  {                                                                          \
    _Pragma("unroll") for (int i = 0; i < 4; ++i)                            \
        GLD(Am + (size_t)(tm + i * 64 + rl) * 2048 + (kt) + scol,            \
            LDS + (buf) * 24576 + i * 4096 + tid * 16);                      \
    _Pragma("unroll") for (int i = 0; i < 2; ++i)                            \
        GLD(Bm + (size_t)(tn + i * 64 + rl) * 2048 + (kt) + scol,            \
            LDS + (buf) * 24576 + 16384 + i * 4096 + tid * 16);              \
  }

  f32x4 acc[8][4] = {};

  STAGEU(0, 0);
  STAGEU(1, 32);
  int cur = 0, st3 = 2;
  for (int t = 0; t < 63; ++t) {
    asm volatile("s_waitcnt vmcnt(6)" ::: "memory");
    __builtin_amdgcn_s_barrier();
    asm volatile("" ::: "memory");
    if (t < 62) STAGEU(st3, (t + 2) * 32);
    const char* pa = LDS + cur * 24576;
    const char* pb = pa + 16384;
    bf16x8 a[8], b[4];
#pragma unroll
    for (int fm = 0; fm < 8; ++fm)
      a[fm] = *reinterpret_cast<const bf16x8*>(pa + (wr * 128 + fm * 16 + lr) * 64 + xo);
#pragma unroll
    for (int nf = 0; nf < 4; ++nf)
      b[nf] = *reinterpret_cast<const bf16x8*>(pb + (wc * 64 + nf * 16 + lr) * 64 + xo);
    __builtin_amdgcn_s_setprio(1);
#pragma unroll
    for (int fm = 0; fm < 8; ++fm)
#pragma unroll
      for (int nf = 0; nf < 4; ++nf)
        acc[fm][nf] = MFMA(a[fm], b[nf], acc[fm][nf]);
    __builtin_amdgcn_s_setprio(0);
    cur = (cur == 2) ? 0 : cur + 1;
    st3 = (st3 == 2) ? 0 : st3 + 1;
  }
  {
    asm volatile("s_waitcnt vmcnt(0)" ::: "memory");
    __builtin_amdgcn_s_barrier();
    asm volatile("" ::: "memory");
    const char* pa = LDS + cur * 24576;
    const char* pb = pa + 16384;
    bf16x8 a[8], b[4];
#pragma unroll
    for (int fm = 0; fm < 8; ++fm)
      a[fm] = *reinterpret_cast<const bf16x8*>(pa + (wr * 128 + fm * 16 + lr) * 64 + xo);
#pragma unroll
    for (int nf = 0; nf < 4; ++nf)
      b[nf] = *reinterpret_cast<const bf16x8*>(pb + (wc * 64 + nf * 16 + lr) * 64 + xo);
#pragma unroll
    for (int fm = 0; fm < 8; ++fm)
#pragma unroll
      for (int nf = 0; nf < 4; ++nf)
        acc[fm][nf] = MFMA(a[fm], b[nf], acc[fm][nf]);
  }

#pragma unroll
  for (int fm = 0; fm < 8; ++fm)
#pragma unroll
    for (int nf = 0; nf < 4; ++nf)
#pragma unroll
      for (int rr = 0; rr < 4; ++rr) {
        int row = tm + wr * 128 + fm * 16 + g * 4 + rr;
        int col = tn + wc * 64 + nf * 16 + lr;
        C[(size_t)row * 2048 + col] = acc[fm][nf][rr];
      }
}

// ---------- causal poly^4 attention (round-10 version, frozen) ----------
__global__ __launch_bounds__(256) void k_attn(const bf16* __restrict__ Q,
                                              const bf16* __restrict__ K,
                                              const bf16* __restrict__ Vt,
                                              bf16* __restrict__ O) {
  __shared__ __align__(16) bf16 Ks[2][64 * 128];  // 32KB
  __shared__ __align__(16) bf16 Vs[2][128 * 64];  // 32KB  [hd][kv]
  __shared__ __align__(16) bf16 Ps[128 * 64];     // 16KB
  const int tid = threadIdx.x, w = tid >> 6, l = tid & 63;
  const int lr = l & 15, g = l >> 4;
  const int qb = 15 - (blockIdx.x >> 5);  // longest first
  const int bh = blockIdx.x & 31;
  const size_t base = (size_t)bh * 2048 * 128;
  const int b_ = bh >> 4, h_ = bh & 15;
  const int qbase = qb * 128;
  const int nt = 2 * qb + 2;

  bf16x8 vones = {};
  if (lr == 0) {
#pragma unroll
    for (int j = 0; j < 8; ++j) vones[j] = (bf16)1.0f;
  }

  bf16x8 qf[2][4];
#pragma unroll
  for (int mi = 0; mi < 2; ++mi)
#pragma unroll
    for (int kc = 0; kc < 4; ++kc)
      qf[mi][kc] = *reinterpret_cast<const bf16x8*>(
          Q + base + (size_t)(qbase + w * 32 + mi * 16 + lr) * 128 + kc * 32 + g * 8);

  f32x4 on[2][8] = {};
  f32x4 dn4[2] = {};

#define STAGEKV(tt, buf)                                                 \
  {                                                                      \
    const bf16* kg = K + base + (size_t)(tt) * 64 * 128;                 \
    _Pragma("unroll") for (int r = 0; r < 4; ++r) {                      \
      int row = r * 16 + w * 4 + (l >> 4);                               \
      int cc = l & 15;                                                   \
      GLD(kg + (row << 7) + ((cc ^ (row & 7)) << 3),                     \
          Ks[buf] + r * 2048 + w * 512);                                 \
    }                                                                    \
    const bf16* vg = Vt + base + (tt) * 64;                              \
    _Pragma("unroll") for (int r = 0; r < 4; ++r) {                      \
      int row = r * 32 + w * 8 + (l >> 3);                               \
      int cc = l & 7;                                                    \
      GLD(vg + (size_t)row * 2048 + ((cc ^ (row & 7)) << 3),             \
          Vs[buf] + r * 2048 + w * 512);                                 \
    }                                                                    \
  }

  STAGEKV(0, 0);

  for (int t = 0; t < nt; ++t) {
    int tn1 = (t + 1 < nt) ? t + 1 : nt - 1;
    STAGEKV(tn1, (t + 1) & 1);
    asm volatile("s_waitcnt vmcnt(8)" ::: "memory");
    __builtin_amdgcn_s_barrier();

    const bf16* kcur = Ks[t & 1];
    const bf16* vcur = Vs[t & 1];

    f32x4 s[2][4] = {};
    __builtin_amdgcn_s_setprio(1);
#pragma unroll
    for (int kc = 0; kc < 4; ++kc) {
      bf16x8 kb[4];
#pragma unroll
      for (int ni = 0; ni < 4; ++ni)
        kb[ni] = *reinterpret_cast<const bf16x8*>(
            kcur + ((ni * 16 + lr) << 7) + (((kc * 4 + g) ^ (lr & 7)) << 3));
#pragma unroll
      for (int mi = 0; mi < 2; ++mi)
#pragma unroll
        for (int ni = 0; ni < 4; ++ni)
          s[mi][ni] = MFMA(qf[mi][kc], kb[ni], s[mi][ni]);
    }
    __builtin_amdgcn_s_setprio(0);

#pragma unroll
    for (int mi = 0; mi < 2; ++mi) {
      const bool msk = (t * 64 + 63 > qbase + w * 32 + mi * 16);
#pragma unroll
      for (int ni = 0; ni < 4; ++ni)
#pragma unroll
        for (int r = 0; r < 4; ++r) {
          int lrow = mi * 16 + g * 4 + r;
          float v = s[mi][ni][r];
          if (msk) {
            int qrow = qbase + w * 32 + lrow;
            int col = t * 64 + ni * 16 + lr;
            v = (col <= qrow) ? v : 0.f;
          }
          float v2 = v * v, v4 = v2 * v2;
          Ps[((w * 32 + lrow) << 6) +
             (((ni * 2 + (lr >> 3)) ^ (lrow & 7)) << 3) + (lr & 7)] = (bf16)v4;
        }
    }

    __builtin_amdgcn_s_setprio(1);
#pragma unroll
    for (int k2 = 0; k2 < 2; ++k2) {
      bf16x8 pa[2];
#pragma unroll
      for (int mi = 0; mi < 2; ++mi)
        pa[mi] = *reinterpret_cast<const bf16x8*>(
            Ps + ((w * 32 + mi * 16 + lr) << 6) + (((k2 * 4 + g) ^ (lr & 7)) << 3));
      dn4[0] = MFMA(pa[0], vones, dn4[0]);
      dn4[1] = MFMA(pa[1], vones, dn4[1]);
#pragma unroll
      for (int ni = 0; ni < 8; ++ni) {
        bf16x8 vbf = *reinterpret_cast<const bf16x8*>(
            vcur + ((ni * 16 + lr) << 6) + (((k2 * 4 + g) ^ (lr & 7)) << 3));
        on[0][ni] = MFMA(pa[0], vbf, on[0][ni]);
        on[1][ni] = MFMA(pa[1], vbf, on[1][ni]);
      }
    }
    __builtin_amdgcn_s_setprio(0);
    __builtin_amdgcn_s_barrier();
  }

  asm volatile("s_waitcnt vmcnt(0)" ::: "memory");

#pragma unroll
  for (int mi = 0; mi < 2; ++mi)
#pragma unroll
    for (int r = 0; r < 4; ++r) {
      float d = __shfl(dn4[mi][r], l & 48);
      float inv = 1.0f / fmaxf(d, 1e-6f);
      int row = qbase + w * 32 + mi * 16 + g * 4 + r;
#pragma unroll
      for (int ni = 0; ni < 8; ++ni)
        O[((size_t)b_ * 2048 + row) * 2048 + h_ * 128 + ni * 16 + lr] =
            (bf16)(on[mi][ni][r] * inv);
    }
#undef STAGEKV
}

extern "C" void kernel_launch(void* const* d_in, const int* in_sizes, int n_in,
                              void* d_out, int out_size, void* d_ws, size_t ws_size,
                              hipStream_t stream) {
  const float* x  = (const float*)d_in[0];
  const float* Wq = (const float*)d_in[1];
  const float* Wk = (const float*)d_in[2];
  const float* Wv = (const float*)d_in[3];
  const float* Wo = (const float*)d_in[4];
  float* out = (float*)d_out;

  char* p = (char*)d_ws;
  bf16* xb   = (bf16*)p; p += (size_t)8388608 * 2;    // x bf16 (4096x2048)
  bf16* wqkv = (bf16*)p; p += (size_t)12582912 * 2;   // [Wq;Wk;Wv] (6144x2048)
  bf16* wob  = (bf16*)p; p += (size_t)4194304 * 2;    // Wo bf16
  bf16* Qp   = (bf16*)p; p += (size_t)8388608 * 2;    // roped (b,h,n,128)
  bf16* Kp   = (bf16*)p; p += (size_t)8388608 * 2;    // roped (b,h,n,128)
  bf16* Vt   = (bf16*)p; p += (size_t)8388608 * 2;    // (b,h,128,n)
  bf16* Ob   = (bf16*)p; p += (size_t)8388608 * 2;    // attn out (b,n,h*128)
  float* ct  = (float*)p; p += (size_t)131072 * 4;
  float* st  = (float*)p; p += (size_t)131072 * 4;

  k_prep<<<25088, 256, 0, stream>>>(x, Wq, Wk, Wv, Wo, xb, wqkv, wob, ct, st);

  k_gemm_qkv<<<dim3(48, 16), 256, 0, stream>>>(xb, wqkv, Qp, Kp, Vt, ct, st);

  k_attn<<<512, 256, 0, stream>>>(Qp, Kp, Vt, Ob);

  k_gemm_out<<<dim3(16, 16), 256, 0, stream>>>(Ob, wob, out);
}